// Round 9
// baseline (8295.297 us; speedup 1.0000x reference)
//
#include <hip/hip_runtime.h>
#include <cstdint>
#include <cstddef>

// Problem constants
#define Bb   128
#define Tt   500
#define INn  306
#define Hh   512
#define GRID 128
#define BH   (Bb * Hh)              // 65536 u16 per h slot

typedef short bf16x8 __attribute__((ext_vector_type(8)));
typedef float f32x4  __attribute__((ext_vector_type(4)));
typedef unsigned short u16t;
typedef unsigned long long u64t;

union F8 { bf16x8 v; uint4 q; unsigned u[4]; u16t s[8]; };

__device__ __forceinline__ float bf2f(u16t h) {
  unsigned u = ((unsigned)h) << 16;
  return __builtin_bit_cast(float, u);
}
__device__ __forceinline__ u16t f2bf(float f) {
  unsigned u = __builtin_bit_cast(unsigned, f);
  unsigned r = u + 0x7fffu + ((u >> 16) & 1u);   // RNE (finite inputs only)
  return (u16t)(r >> 16);
}
__device__ __forceinline__ void splitRNE(float v, u16t& hi, u16t& lo) {
  hi = f2bf(v);
  lo = f2bf(v - bf2f(hi));
}
__device__ __forceinline__ void splitTR(float v, u16t& hi, u16t& lo) {
  unsigned u = __builtin_bit_cast(unsigned, v);
  hi = (u16t)(u >> 16);
  float hf = __builtin_bit_cast(float, u & 0xFFFF0000u);
  lo = (u16t)(__builtin_bit_cast(unsigned, v - hf) >> 16);
}
__device__ __forceinline__ f32x4 MF(const F8& a, const F8& b, f32x4 c) {
  return __builtin_amdgcn_mfma_f32_16x16x32_bf16(a.v, b.v, c, 0, 0, 0);
}

// Device-coherent point accesses (relaxed agent atomics -> sc1 instructions;
// no bulk cache maintenance anywhere in this kernel).
__device__ __forceinline__ void stsh(u16t* p, u16t v) {
  __hip_atomic_store(p, v, __ATOMIC_RELAXED, __HIP_MEMORY_SCOPE_AGENT);
}
__device__ __forceinline__ F8 ld8(const u16t* p) {   // 16B-aligned
  const u64t* q = (const u64t*)p;
  u64t a = __hip_atomic_load(q,     __ATOMIC_RELAXED, __HIP_MEMORY_SCOPE_AGENT);
  u64t b = __hip_atomic_load(q + 1, __ATOMIC_RELAXED, __HIP_MEMORY_SCOPE_AGENT);
  F8 r;
  r.u[0] = (unsigned)a; r.u[1] = (unsigned)(a >> 32);
  r.u[2] = (unsigned)b; r.u[3] = (unsigned)(b >> 32);
  return r;
}

// 1-hop group barrier, split into signal/wait. flags[2][16] parity slots.
// Invariant: a WG signals s only after completing wait(s-1) (except the
// provably-safe initial signals), so overwriting slot value s-2 is race-free.
// Poison 0xAAAAAAAA never equals s in [1,502].
__device__ __forceinline__ void signal(unsigned* fl, int sub, int tid, unsigned s) {
  asm volatile("s_waitcnt vmcnt(0)" ::: "memory");   // drain own sc1 stores to IF$
  __syncthreads();                                   // all threads drained
  if (tid == 0)
    __hip_atomic_store(&fl[(s & 1) * 16 + sub], s,
                       __ATOMIC_RELAXED, __HIP_MEMORY_SCOPE_AGENT);
}
__device__ __forceinline__ void waitp(unsigned* fl, int tid, unsigned s) {
  if (tid < 64) {                                    // wave 0 polls all 16 flags
    unsigned v;
    do {
      v = (tid < 16) ? __hip_atomic_load(&fl[(s & 1) * 16 + tid],
                                         __ATOMIC_RELAXED, __HIP_MEMORY_SCOPE_AGENT)
                     : s;
    } while (__ballot(v == s) != ~0ull);
  }
  __syncthreads();
}

__global__ __launch_bounds__(256, 1) void rnn_all(
    const float* x,
    const float* Wih0, const float* Whh0, const float* bih0, const float* bhh0,
    const float* Wih1, const float* Whh1, const float* bih1, const float* bhh1,
    const float* Wfc,  const float* bfc,
    float* out, unsigned char* ws)
{
  const int wg   = blockIdx.x;
  const int g    = wg >> 4;            // row-group 0..7 (16 batch rows each)
  const int sub  = wg & 15;            // 0..7 = L0 col-slices, 8..15 = L1
  const int tid  = threadIdx.x;
  const int lane = tid & 63;
  const int wave = tid >> 6;
  const int l15  = lane & 15;
  const int quad = lane >> 4;

  unsigned* fl = (unsigned*)(ws + (size_t)g * 256);  // flags[2][16] per group
  u16t* hbase = (u16t*)(ws + 4096);
  u16t* h0hi = hbase;                  // [2 slots][128][512] each plane
  u16t* h0lo = hbase + 2 * BH;
  u16t* h1hi = hbase + 4 * BH;
  u16t* h1lo = hbase + 6 * BH;

  // Zero THIS GROUP's h rows: 8 regions x (16 rows x 512) u16. 512 threads per
  // region, 16 u16 (4 u64 stores) per thread -> full coverage (R8 covered half
  // and survived on poison-is-denormal luck; now exact).
  {
    const int tg  = sub * 256 + tid;        // 0..4095
    const int reg = tg >> 9;                // 0..7 = (plane<<1)|slot
    const int pos = tg & 511;               // 16-elem chunk within 16x512
    u64t* dq = (u64t*)(hbase + (size_t)(reg >> 1) * 2 * BH
                             + (size_t)(reg & 1) * BH
                             + (size_t)g * 8192 + (size_t)pos * 16);
#pragma unroll
    for (int i = 0; i < 4; ++i)
      __hip_atomic_store(dq + i, 0ull, __ATOMIC_RELAXED, __HIP_MEMORY_SCOPE_AGENT);
  }

  // Tiling: rows = g*16..g*16+15; cols = 64 per WG (wave*16 within).
  const bool isL0 = (sub < 8);
  const int Mb    = g * 16;
  const int Jb    = (isL0 ? sub : sub - 8) * 64;
  const int jn    = Jb + wave * 16 + l15;     // output col / B-row
  const int rowA  = Mb + l15;                 // A-row this lane loads
  const int mOutB = Mb + quad * 4;            // C/D: row = quad*4 + r

  if (isL0) {
    // ---------------- Layer 0 ----------------
    F8 Bxh[10], Bxl[10], Bhh[16], Bhl[16];
#pragma unroll
    for (int kc = 0; kc < 10; ++kc) {
#pragma unroll
      for (int e = 0; e < 8; ++e) {
        const int k = kc * 32 + quad * 8 + e;
        float v = (k < INn) ? Wih0[(size_t)jn * INn + k] : 0.f;
        splitRNE(v, Bxh[kc].s[e], Bxl[kc].s[e]);
      }
    }
#pragma unroll
    for (int kc = 0; kc < 16; ++kc) {
      const float* wr = Whh0 + (size_t)jn * Hh + kc * 32 + quad * 8;
#pragma unroll
      for (int e = 0; e < 8; ++e)
        splitRNE(wr[e], Bhh[kc].s[e], Bhl[kc].s[e]);
    }
    const float bv = bih0[jn] + bhh0[jn];

    signal(fl, sub, tid, 1u);                        // zeros drained+flagged

    for (int t = 0; t < Tt; ++t) {
      // ---- x part FIRST (independent of h): runs in the wait shadow ----
      F8 xh[10], xl[10];
      {
        const float* xr = x + ((size_t)rowA * Tt + t) * INn;  // 8B-aligned
#pragma unroll
        for (int kc = 0; kc < 10; ++kc) {
          const int kb = kc * 32 + quad * 8;
          float v[8];
          if (kc < 9) {
            const float2* p = (const float2*)(xr + kb);
#pragma unroll
            for (int h2 = 0; h2 < 4; ++h2) {
              float2 w = p[h2];
              v[2 * h2] = w.x; v[2 * h2 + 1] = w.y;
            }
          } else {
#pragma unroll
            for (int e = 0; e < 8; ++e)
              v[e] = (kb + e < INn) ? xr[kb + e] : 0.f;
          }
#pragma unroll
          for (int e = 0; e < 8; ++e) splitTR(v[e], xh[kc].s[e], xl[kc].s[e]);
        }
      }
      f32x4 ac0 = {bv, bv, bv, bv};
      f32x4 ac1 = {0.f, 0.f, 0.f, 0.f};
      f32x4 ac2 = {0.f, 0.f, 0.f, 0.f};
#pragma unroll
      for (int kc = 0; kc < 10; ++kc) {
        ac0 = MF(xh[kc], Bxh[kc], ac0);
        ac1 = MF(xh[kc], Bxl[kc], ac1);
        ac2 = MF(xl[kc], Bxh[kc], ac2);
      }

      waitp(fl, tid, (unsigned)(t + 1));             // h0(t-1) visible at IF$

      const int ps = (t + 1) & 1, cs = t & 1;
      const u16t* phi = h0hi + (size_t)ps * BH + (size_t)rowA * Hh + quad * 8;
      const u16t* plo = h0lo + (size_t)ps * BH + (size_t)rowA * Hh + quad * 8;
#pragma unroll
      for (int kc = 0; kc < 16; ++kc) {
        F8 ah = ld8(phi + kc * 32);
        F8 al = ld8(plo + kc * 32);
        ac0 = MF(ah, Bhh[kc], ac0);
        ac1 = MF(ah, Bhl[kc], ac1);
        ac2 = MF(al, Bhh[kc], ac2);
      }
      u16t* shi = h0hi + (size_t)cs * BH;
      u16t* slo = h0lo + (size_t)cs * BH;
#pragma unroll
      for (int r = 0; r < 4; ++r) {
        const float v = tanhf(ac0[r] + ac1[r] + ac2[r]);
        u16t hb, lb; splitRNE(v, hb, lb);
        const size_t m = (size_t)(mOutB + r) * Hh;
        stsh(shi + m + jn, hb);
        stsh(slo + m + jn, lb);
      }
      signal(fl, sub, tid, (unsigned)(t + 2));
    }
    waitp(fl, tid, 501u);
    signal(fl, sub, tid, 502u);                      // complete the phase count
  } else {
    // ---------------- Layer 1 ----------------
    F8 Bih[16], Bil[16], Bh2[16], Bl2[16];
#pragma unroll
    for (int kc = 0; kc < 16; ++kc) {
      const float* w1 = Wih1 + (size_t)jn * Hh + kc * 32 + quad * 8;
      const float* w2 = Whh1 + (size_t)jn * Hh + kc * 32 + quad * 8;
#pragma unroll
      for (int e = 0; e < 8; ++e) {
        splitRNE(w1[e], Bih[kc].s[e], Bil[kc].s[e]);
        splitRNE(w2[e], Bh2[kc].s[e], Bl2[kc].s[e]);
      }
    }
    const float bv = bih1[jn] + bhh1[jn];

    signal(fl, sub, tid, 1u);                        // zeros drained+flagged
    signal(fl, sub, tid, 2u);                        // no phase-2 work for L1

    for (int t1 = 0; t1 < Tt; ++t1) {
      waitp(fl, tid, (unsigned)(t1 + 2));            // h0(t1) & h1(t1-1) visible

      const int s0  = t1 & 1;
      const int s1r = (t1 + 1) & 1;
      const u16t* p0h = h0hi + (size_t)s0  * BH + (size_t)rowA * Hh + quad * 8;
      const u16t* p0l = h0lo + (size_t)s0  * BH + (size_t)rowA * Hh + quad * 8;
      const u16t* p1h = h1hi + (size_t)s1r * BH + (size_t)rowA * Hh + quad * 8;
      const u16t* p1l = h1lo + (size_t)s1r * BH + (size_t)rowA * Hh + quad * 8;
      f32x4 ac0 = {bv, bv, bv, bv};
      f32x4 ac1 = {0.f, 0.f, 0.f, 0.f};
      f32x4 ac2 = {0.f, 0.f, 0.f, 0.f};
#pragma unroll
      for (int kc = 0; kc < 16; ++kc) {
        F8 ah = ld8(p0h + kc * 32);
        F8 al = ld8(p0l + kc * 32);
        ac0 = MF(ah, Bih[kc], ac0);
        ac1 = MF(ah, Bil[kc], ac1);
        ac2 = MF(al, Bih[kc], ac2);
      }
#pragma unroll
      for (int kc = 0; kc < 16; ++kc) {
        F8 ah = ld8(p1h + kc * 32);
        F8 al = ld8(p1l + kc * 32);
        ac0 = MF(ah, Bh2[kc], ac0);
        ac1 = MF(ah, Bl2[kc], ac1);
        ac2 = MF(al, Bh2[kc], ac2);
      }
      u16t* shi = h1hi + (size_t)(t1 & 1) * BH;
      u16t* slo = h1lo + (size_t)(t1 & 1) * BH;
#pragma unroll
      for (int r = 0; r < 4; ++r) {
        const float v = tanhf(ac0[r] + ac1[r] + ac2[r]);
        u16t hb, lb; splitRNE(v, hb, lb);
        const size_t m = (size_t)(mOutB + r) * Hh;
        stsh(shi + m + jn, hb);
        stsh(slo + m + jn, lb);
      }
      signal(fl, sub, tid, (unsigned)(t1 + 3));
    }

    // ---- FC + softmax for this group's 16 rows (sub==8). f32 output. ----
    if (sub == 8) {
      waitp(fl, tid, 502u);
      if (tid < 16) {
        const int b = Mb + tid;
        const u16t* hh = h1hi + (size_t)1 * BH + (size_t)b * Hh;
        const u16t* hl = h1lo + (size_t)1 * BH + (size_t)b * Hh;
        float acc[4] = {bfc[0], bfc[1], bfc[2], bfc[3]};
        for (int j8 = 0; j8 < Hh; j8 += 8) {
          F8 a = ld8(hh + j8);           // coherent: local L2 may hold stale 0s
          F8 c = ld8(hl + j8);
#pragma unroll
          for (int e = 0; e < 8; ++e) {
            const float hv = bf2f(a.s[e]) + bf2f(c.s[e]);
#pragma unroll
            for (int cc = 0; cc < 4; ++cc)
              acc[cc] += hv * Wfc[cc * Hh + j8 + e];
          }
        }
        const float mx = fmaxf(fmaxf(acc[0], acc[1]), fmaxf(acc[2], acc[3]));
        const float e0 = expf(acc[0] - mx), e1 = expf(acc[1] - mx);
        const float e2 = expf(acc[2] - mx), e3 = expf(acc[3] - mx);
        const float si = 1.f / (e0 + e1 + e2 + e3);
        out[b * 4 + 0] = e0 * si;
        out[b * 4 + 1] = e1 * si;
        out[b * 4 + 2] = e2 * si;
        out[b * 4 + 3] = e3 * si;
      }
    }
  }
}

extern "C" void kernel_launch(void* const* d_in, const int* in_sizes, int n_in,
                              void* d_out, int out_size, void* d_ws, size_t ws_size,
                              hipStream_t stream) {
  const float* x    = (const float*)d_in[0];
  const float* Wih0 = (const float*)d_in[1];
  const float* Whh0 = (const float*)d_in[2];
  const float* bih0 = (const float*)d_in[3];
  const float* bhh0 = (const float*)d_in[4];
  const float* Wih1 = (const float*)d_in[5];
  const float* Whh1 = (const float*)d_in[6];
  const float* bih1 = (const float*)d_in[7];
  const float* bhh1 = (const float*)d_in[8];
  const float* Wfc  = (const float*)d_in[9];
  const float* bfc  = (const float*)d_in[10];
  float* out = (float*)d_out;
  unsigned char* ws = (unsigned char*)d_ws;

  rnn_all<<<dim3(GRID), dim3(256), 0, stream>>>(
      x, Wih0, Whh0, bih0, bhh0, Wih1, Whh1, bih1, bhh1, Wfc, bfc, out, ws);
}